// Round 3
// baseline (370.798 us; speedup 1.0000x reference)
//
#include <hip/hip_runtime.h>
#include <hip/hip_bf16.h>
#include <math.h>

// Problem constants
#define NM 1024         // molecules
#define NA 32           // atoms per molecule
#define ZD 64           // z dim
#define HD 256          // hidden
#define AT 10           // atom types
#define BT 5            // bond types
#define NROWS (NM*NA)   // 32768
#define EPM 496         // edges per molecule (C(32,2))
#define ATOM_OUT (NROWS*AT)  // 327680

// ---------------------------------------------------------------------------
// K1: Gram matrix M = Z^T Z (64x64) and column sums of Z.
// Grid 128 x 256 threads; each block does 2 chunks of 128 rows through a
// 32KB LDS tile (float4-staged), then 16+1 fp32 atomics per thread.
// ---------------------------------------------------------------------------
__global__ __launch_bounds__(256) void k1_moments(const float* __restrict__ z,
                                                  float* __restrict__ Msum,
                                                  float* __restrict__ sumz) {
    __shared__ __align__(16) float zs[128][64];   // 32 KB
    __shared__ float sred[4][64];
    const int tid = threadIdx.x;
    const int d0 = (tid >> 4) << 2;               // 0..60
    const int e0 = (tid & 15) << 2;
    const int d = tid & 63, rq = tid >> 6;
    float acc[4][4] = {};
    float colsum = 0.f;
    for (int chunk = 0; chunk < 2; ++chunk) {
        const int rowbase = (blockIdx.x * 2 + chunk) * 128;
        __syncthreads();                          // protect zs reuse across chunks
        const float4* zg4 = (const float4*)(z + rowbase * 64);
        float4* zs4 = (float4*)zs;
        #pragma unroll
        for (int k = 0; k < 8; ++k) zs4[tid + (k << 8)] = zg4[tid + (k << 8)];
        __syncthreads();
        for (int r = 0; r < 128; ++r) {
            float4 a4 = *(const float4*)&zs[r][d0];
            float4 b4 = *(const float4*)&zs[r][e0];
            float a[4] = {a4.x, a4.y, a4.z, a4.w};
            float b[4] = {b4.x, b4.y, b4.z, b4.w};
            #pragma unroll
            for (int i = 0; i < 4; ++i)
                #pragma unroll
                for (int jj = 0; jj < 4; ++jj) acc[i][jj] += a[i] * b[jj];
        }
        for (int r = rq * 32; r < rq * 32 + 32; ++r) colsum += zs[r][d];
    }
    #pragma unroll
    for (int i = 0; i < 4; ++i)
        #pragma unroll
        for (int jj = 0; jj < 4; ++jj)
            atomicAdd(&Msum[(d0 + i) * 64 + (e0 + jj)], acc[i][jj]);
    sred[rq][d] = colsum;
    __syncthreads();
    if (tid < 64)
        atomicAdd(&sumz[tid], sred[0][tid] + sred[1][tid] + sred[2][tid] + sred[3][tid]);
}

// ---------------------------------------------------------------------------
// K2W: (a) blocks 0..63: fold BN into per-channel affine h_bn = (z@W1)*a + c.
// (b) blocks 64..143: Wsym[t] = 0.5*(B[t]+B[t]^T)  (20480 elems).
// ---------------------------------------------------------------------------
__global__ __launch_bounds__(256) void k2w(const float* __restrict__ Msum,
                                           const float* __restrict__ sumz,
                                           const float* __restrict__ W1,
                                           const float* __restrict__ gamma,
                                           const float* __restrict__ beta,
                                           const float* __restrict__ bond,
                                           float* __restrict__ avec,
                                           float* __restrict__ cvec,
                                           float* __restrict__ Wsym) {
    const int tid = threadIdx.x;
    if (blockIdx.x >= 64) {
        int idx = ((int)blockIdx.x - 64) * 256 + tid;   // 0..20479
        int t = idx >> 12, rem = idx & 4095, dd = rem >> 6, c = rem & 63;
        Wsym[idx] = 0.5f * (bond[(t << 12) + (dd << 6) + c] +
                            bond[(t << 12) + (c << 6) + dd]);
        return;
    }
    const int wv = tid >> 6, d = tid & 63;
    const int j = blockIdx.x * 4 + wv;                  // 0..255
    const float wdj = W1[d * HD + j];
    float v = 0.f;
    for (int e = 0; e < 64; ++e) v += Msum[d * 64 + e] * W1[e * HD + j];
    float q = v * wdj;
    float s = sumz[d] * wdj;
    #pragma unroll
    for (int off = 32; off >= 1; off >>= 1) {
        q += __shfl_down(q, off);
        s += __shfl_down(s, off);
    }
    if (d == 0) {
        const float invN = 1.f / (float)NROWS;
        float mean = s * invN;
        float var = q * invN - mean * mean;
        float a = gamma[j] * rsqrtf(var + 1e-5f);
        avec[j] = a;
        cvec[j] = beta[j] - mean * a;
    }
}

// ---------------------------------------------------------------------------
// K3: fused MLP: atom_types = gelu((z@W1)*a + c) @ W2 + b2
// 1024 blocks x 32 rows, 256 threads. Thread tile: 2 rows x 16 channels.
// LDS 38KB -> 4 blocks/CU = 16 waves/CU (was 2 blocks, 8 waves).
// ---------------------------------------------------------------------------
__global__ __launch_bounds__(256, 4) void k3_mlp(const float* __restrict__ z,
                                                 const float* __restrict__ W1,
                                                 const float* __restrict__ W2,
                                                 const float* __restrict__ b2,
                                                 const float* __restrict__ avec,
                                                 const float* __restrict__ cvec,
                                                 float* __restrict__ out_atom) {
    __shared__ __align__(16) float zsT[64][36];   // [d][row], 9.2 KB
    __shared__ __align__(16) float w1s[16][256];  // one 16-d chunk of W1, 16 KB
    __shared__ float w2s[256][11];                // stride 11 -> no 4-way conflict
    __shared__ float as[256], cs[256];
    const int tid = threadIdx.x;
    const int rowbase = blockIdx.x * 32;
    {   // stage z (32x64) transposed: thread -> row tid>>3, d-range (tid&7)*8
        const float* zp = z + (size_t)(rowbase + (tid >> 3)) * 64 + (tid & 7) * 8;
        float4 v0 = *(const float4*)zp;
        float4 v1 = *(const float4*)(zp + 4);
        const int r = tid >> 3, dbase = (tid & 7) * 8;
        zsT[dbase + 0][r] = v0.x; zsT[dbase + 1][r] = v0.y;
        zsT[dbase + 2][r] = v0.z; zsT[dbase + 3][r] = v0.w;
        zsT[dbase + 4][r] = v1.x; zsT[dbase + 5][r] = v1.y;
        zsT[dbase + 6][r] = v1.z; zsT[dbase + 7][r] = v1.w;
    }
    for (int k = tid; k < HD * AT; k += 256) w2s[k / 10][k % 10] = W2[k];
    as[tid] = avec[tid]; cs[tid] = cvec[tid];

    const int rg = tid >> 4, cg = tid & 15;
    const int r0 = rg << 1;                       // 2 rows per thread
    float acc[2][4][4] = {};                      // [row][cblock][u]
    for (int ch = 0; ch < 4; ++ch) {
        __syncthreads();                          // w1s reuse (and staging on ch=0)
        #pragma unroll
        for (int k = 0; k < 16; ++k) {
            int idx = tid + (k << 8);
            ((float*)w1s)[idx] = W1[(ch << 12) + idx];
        }
        __syncthreads();
        #pragma unroll
        for (int dl = 0; dl < 16; ++dl) {
            float zr0 = zsT[(ch << 4) + dl][r0];
            float zr1 = zsT[(ch << 4) + dl][r0 + 1];
            #pragma unroll
            for (int cb = 0; cb < 4; ++cb) {
                float4 wv = *(const float4*)&w1s[dl][(cb << 6) + (cg << 2)];
                float wr[4] = {wv.x, wv.y, wv.z, wv.w};
                #pragma unroll
                for (int u = 0; u < 4; ++u) {
                    acc[0][cb][u] += zr0 * wr[u];
                    acc[1][cb][u] += zr1 * wr[u];
                }
            }
        }
    }
    // epilogue: affine + exact gelu + GEMM2 partials
    float p[2][10] = {};
    #pragma unroll
    for (int cb = 0; cb < 4; ++cb)
        #pragma unroll
        for (int u = 0; u < 4; ++u) {
            const int c = (cb << 6) + (cg << 2) + u;
            const float a = as[c], cc = cs[c];
            #pragma unroll
            for (int ri = 0; ri < 2; ++ri) {
                float h = acc[ri][cb][u] * a + cc;
                h = 0.5f * h * (1.0f + erff(h * 0.70710678118654752f));
                #pragma unroll
                for (int o = 0; o < 10; ++o) p[ri][o] += h * w2s[c][o];
            }
        }
    #pragma unroll
    for (int m = 1; m <= 8; m <<= 1)
        #pragma unroll
        for (int ri = 0; ri < 2; ++ri)
            #pragma unroll
            for (int o = 0; o < 10; ++o) p[ri][o] += __shfl_xor(p[ri][o], m);
    if (cg == 0) {
        #pragma unroll
        for (int ri = 0; ri < 2; ++ri)
            for (int o = 0; o < 10; ++o)
                out_atom[(size_t)(rowbase + r0 + ri) * AT + o] = p[ri][o] + b2[o];
    }
}

// ---------------------------------------------------------------------------
// K4: edges. Block = 1 molecule, 256 threads, grid 1024. LDS 21KB,
// <=128 VGPR -> 16 waves/CU (was 8).
// d processed in 4 quarters of 16. Per quarter:
//  Phase A: u[t][j][dloc] = sum_c Wsym[t][d][c]*z_j[c].
//    Lanes = 32 j x 2 c-halves; wave wv owns d = qd*16+wv*4+dd (wave-uniform
//    row addresses, contiguous 128B vector loads, L2-hot). z half-row lives in
//    32 VGPRs (no repeated LDS reads -> kills the 7.86M bank-conflict source).
//    c-halves combined with one shfl_xor(32).
//  Phase B: accE[t][i] += z_i[d-chunk] . u[t][j][d-chunk]; 1 j-col/thread,
//    4-row i tile; z reads are same-address broadcasts, uT rows stride 5
//    16B-slots (odd -> minimal conflict).
// Then per-thread softmax over 5 types, direct write in combinations order.
// ---------------------------------------------------------------------------
__global__ __launch_bounds__(256, 4) void k4_edges(const float* __restrict__ z,
                                                   const float* __restrict__ Wsym,
                                                   float* __restrict__ out_edge) {
    __shared__ __align__(16) float zs[32][64];      // 8 KB (phase-B broadcast reads)
    __shared__ __align__(16) float uT[5][32][20];   // [t][j][dloc(16)+pad4] 12.8 KB
    const int tid = threadIdx.x;
    const int mol = blockIdx.x;
    // stage zs (coalesced, once)
    {
        const float4* zg4 = (const float4*)(z + (size_t)mol * 2048);
        float4* zs4 = (float4*)zs;
        zs4[tid] = zg4[tid];
        zs4[tid + 256] = zg4[tid + 256];
    }
    // phase-A ids and z half-row in registers
    const int wv = tid >> 6;                        // 0..3, wave-uniform
    const int lane = tid & 63;
    const int jA = lane & 31;
    const int ch = lane >> 5;                       // c-half
    float zr[32];
    {
        const float* zrow = z + ((size_t)mol * 32 + jA) * 64 + ch * 32;
        #pragma unroll
        for (int k = 0; k < 8; ++k) {
            float4 v = *(const float4*)(zrow + (k << 2));
            zr[4 * k + 0] = v.x; zr[4 * k + 1] = v.y;
            zr[4 * k + 2] = v.z; zr[4 * k + 3] = v.w;
        }
    }
    // phase-B ids
    const int jg = tid & 31;
    const int ig = tid >> 5;                        // 0..7
    const int i0 = ig << 2;
    float accE[5][4] = {};

    for (int qd = 0; qd < 4; ++qd) {
        // ---- Phase A (registers only) ----
        float accA[5][4];
        #pragma unroll
        for (int t = 0; t < 5; ++t)
            #pragma unroll
            for (int dd = 0; dd < 4; ++dd) {
                const float* wrow = Wsym + (size_t)((t << 6) + (qd << 4) + (wv << 2) + dd) * 64
                                        + (ch << 5);
                float a = 0.f;
                #pragma unroll
                for (int cc = 0; cc < 8; ++cc) {
                    float4 w4 = *(const float4*)(wrow + (cc << 2));
                    a += w4.x * zr[4 * cc] + w4.y * zr[4 * cc + 1]
                       + w4.z * zr[4 * cc + 2] + w4.w * zr[4 * cc + 3];
                }
                accA[t][dd] = a;
            }
        #pragma unroll
        for (int t = 0; t < 5; ++t)
            #pragma unroll
            for (int dd = 0; dd < 4; ++dd)
                accA[t][dd] += __shfl_xor(accA[t][dd], 32);
        __syncthreads();                            // prev phase B done with uT (also zs staged)
        if (ch == 0) {
            #pragma unroll
            for (int t = 0; t < 5; ++t) {
                float4 w; w.x = accA[t][0]; w.y = accA[t][1];
                w.z = accA[t][2]; w.w = accA[t][3];
                *(float4*)&uT[t][jA][wv << 2] = w;
            }
        }
        __syncthreads();                            // uT ready
        // ---- Phase B ----
        #pragma unroll
        for (int cq = 0; cq < 4; ++cq) {
            const int gd = (qd << 4) + (cq << 2);
            float4 u4[5];
            #pragma unroll
            for (int t = 0; t < 5; ++t) u4[t] = *(const float4*)&uT[t][jg][cq << 2];
            #pragma unroll
            for (int ri = 0; ri < 4; ++ri) {
                float4 zv = *(const float4*)&zs[i0 + ri][gd];
                #pragma unroll
                for (int t = 0; t < 5; ++t)
                    accE[t][ri] += zv.x * u4[t].x + zv.y * u4[t].y
                                 + zv.z * u4[t].z + zv.w * u4[t].w;
            }
        }
        __syncthreads();                            // phase B done before next A writes
    }
    // softmax over 5 types + write (combinations order, i < j)
    const int ebase = mol * EPM;
    #pragma unroll
    for (int ri = 0; ri < 4; ++ri) {
        const int i = i0 + ri, j = jg;
        if (i < j) {
            float l0 = accE[0][ri], l1 = accE[1][ri], l2 = accE[2][ri];
            float l3 = accE[3][ri], l4 = accE[4][ri];
            float m = fmaxf(fmaxf(fmaxf(l0, l1), fmaxf(l2, l3)), l4);
            float e0 = expf(l0 - m), e1 = expf(l1 - m), e2 = expf(l2 - m);
            float e3 = expf(l3 - m), e4 = expf(l4 - m);
            float inv = 1.0f / (e0 + e1 + e2 + e3 + e4);
            int p = 31 * i - ((i * (i - 1)) >> 1) + (j - i - 1);
            float* o = out_edge + (size_t)(ebase + p) * 5;
            o[0] = e0 * inv; o[1] = e1 * inv; o[2] = e2 * inv;
            o[3] = e3 * inv; o[4] = e4 * inv;
        }
    }
}

// ---------------------------------------------------------------------------
extern "C" void kernel_launch(void* const* d_in, const int* in_sizes, int n_in,
                              void* d_out, int out_size, void* d_ws, size_t ws_size,
                              hipStream_t stream) {
    (void)in_sizes; (void)n_in; (void)out_size; (void)ws_size;
    const float* z     = (const float*)d_in[0];
    const float* W1    = (const float*)d_in[1];
    // d_in[2] = b1 : cancels exactly in BN -> unused
    const float* gamma = (const float*)d_in[3];
    const float* beta  = (const float*)d_in[4];
    const float* W2    = (const float*)d_in[5];
    const float* b2    = (const float*)d_in[6];
    const float* bond  = (const float*)d_in[7];
    // d_in[8] = edge_index : deterministic combinations order, recomputed -> unused
    float* out = (float*)d_out;
    float* ws  = (float*)d_ws;

    float* Msum = ws;              // 4096
    float* sumz = ws + 4096;       // 64
    float* avec = ws + 4160;       // 256
    float* cvec = ws + 4416;       // 256
    float* Wsym = ws + 4672;       // 20480

    hipMemsetAsync(ws, 0, (4096 + 64) * sizeof(float), stream);
    k1_moments<<<128, 256, 0, stream>>>(z, Msum, sumz);
    k2w<<<144, 256, 0, stream>>>(Msum, sumz, W1, gamma, beta, bond, avec, cvec, Wsym);
    k3_mlp<<<1024, 256, 0, stream>>>(z, W1, W2, b2, avec, cvec, out);
    k4_edges<<<1024, 256, 0, stream>>>(z, Wsym, out + ATOM_OUT);
}

// Round 4
// 240.099 us; speedup vs baseline: 1.5444x; 1.5444x over previous
//
#include <hip/hip_runtime.h>
#include <hip/hip_bf16.h>
#include <math.h>

// Problem constants
#define NM 1024         // molecules
#define NA 32           // atoms per molecule
#define ZD 64           // z dim
#define HD 256          // hidden
#define AT 10           // atom types
#define BT 5            // bond types
#define NROWS (NM*NA)   // 32768
#define EPM 496         // edges per molecule (C(32,2))
#define ATOM_OUT (NROWS*AT)  // 327680

// NOTE (round-3 lesson): __launch_bounds__ with a second argument on this
// toolchain clamped k4 to 64 VGPRs and produced ~500 MB/dispatch of scratch
// spill traffic (FETCH 238 MB + WRITE 275 MB, 2.2x slowdown). Never pass it.

// ---------------------------------------------------------------------------
// K1: Gram matrix M = Z^T Z (64x64) and column sums of Z.
// Grid 128 x 256 threads; 2 chunks of 128 rows through a 32KB LDS tile.
// ---------------------------------------------------------------------------
__global__ __launch_bounds__(256) void k1_moments(const float* __restrict__ z,
                                                  float* __restrict__ Msum,
                                                  float* __restrict__ sumz) {
    __shared__ __align__(16) float zs[128][64];   // 32 KB
    __shared__ float sred[4][64];
    const int tid = threadIdx.x;
    const int d0 = (tid >> 4) << 2;               // 0..60
    const int e0 = (tid & 15) << 2;
    const int d = tid & 63, rq = tid >> 6;
    float acc[4][4] = {};
    float colsum = 0.f;
    for (int chunk = 0; chunk < 2; ++chunk) {
        const int rowbase = (blockIdx.x * 2 + chunk) * 128;
        __syncthreads();                          // protect zs reuse across chunks
        const float4* zg4 = (const float4*)(z + rowbase * 64);
        float4* zs4 = (float4*)zs;
        #pragma unroll
        for (int k = 0; k < 8; ++k) zs4[tid + (k << 8)] = zg4[tid + (k << 8)];
        __syncthreads();
        for (int r = 0; r < 128; ++r) {
            float4 a4 = *(const float4*)&zs[r][d0];
            float4 b4 = *(const float4*)&zs[r][e0];
            float a[4] = {a4.x, a4.y, a4.z, a4.w};
            float b[4] = {b4.x, b4.y, b4.z, b4.w};
            #pragma unroll
            for (int i = 0; i < 4; ++i)
                #pragma unroll
                for (int jj = 0; jj < 4; ++jj) acc[i][jj] += a[i] * b[jj];
        }
        for (int r = rq * 32; r < rq * 32 + 32; ++r) colsum += zs[r][d];
    }
    #pragma unroll
    for (int i = 0; i < 4; ++i)
        #pragma unroll
        for (int jj = 0; jj < 4; ++jj)
            atomicAdd(&Msum[(d0 + i) * 64 + (e0 + jj)], acc[i][jj]);
    sred[rq][d] = colsum;
    __syncthreads();
    if (tid < 64)
        atomicAdd(&sumz[tid], sred[0][tid] + sred[1][tid] + sred[2][tid] + sred[3][tid]);
}

// ---------------------------------------------------------------------------
// K2W: (a) blocks 0..63: fold BN into per-channel affine h_bn = (z@W1)*a + c.
// (b) blocks 64..143: Wsym[t] = 0.5*(B[t]+B[t]^T)  (20480 elems).
// ---------------------------------------------------------------------------
__global__ __launch_bounds__(256) void k2w(const float* __restrict__ Msum,
                                           const float* __restrict__ sumz,
                                           const float* __restrict__ W1,
                                           const float* __restrict__ gamma,
                                           const float* __restrict__ beta,
                                           const float* __restrict__ bond,
                                           float* __restrict__ avec,
                                           float* __restrict__ cvec,
                                           float* __restrict__ Wsym) {
    const int tid = threadIdx.x;
    if (blockIdx.x >= 64) {
        int idx = ((int)blockIdx.x - 64) * 256 + tid;   // 0..20479
        int t = idx >> 12, rem = idx & 4095, dd = rem >> 6, c = rem & 63;
        Wsym[idx] = 0.5f * (bond[(t << 12) + (dd << 6) + c] +
                            bond[(t << 12) + (c << 6) + dd]);
        return;
    }
    const int wv = tid >> 6, d = tid & 63;
    const int j = blockIdx.x * 4 + wv;                  // 0..255
    const float wdj = W1[d * HD + j];
    float v = 0.f;
    for (int e = 0; e < 64; ++e) v += Msum[d * 64 + e] * W1[e * HD + j];
    float q = v * wdj;
    float s = sumz[d] * wdj;
    #pragma unroll
    for (int off = 32; off >= 1; off >>= 1) {
        q += __shfl_down(q, off);
        s += __shfl_down(s, off);
    }
    if (d == 0) {
        const float invN = 1.f / (float)NROWS;
        float mean = s * invN;
        float var = q * invN - mean * mean;
        float a = gamma[j] * rsqrtf(var + 1e-5f);
        avec[j] = a;
        cvec[j] = beta[j] - mean * a;
    }
}

// ---------------------------------------------------------------------------
// K3: fused MLP: atom_types = gelu((z@W1)*a + c) @ W2 + b2
// 1024 blocks x 32 rows, 256 threads. Thread tile: 2 rows x 16 channels.
// LDS ~39KB. No launch-bounds occupancy hint (see note above).
// ---------------------------------------------------------------------------
__global__ __launch_bounds__(256) void k3_mlp(const float* __restrict__ z,
                                              const float* __restrict__ W1,
                                              const float* __restrict__ W2,
                                              const float* __restrict__ b2,
                                              const float* __restrict__ avec,
                                              const float* __restrict__ cvec,
                                              float* __restrict__ out_atom) {
    __shared__ __align__(16) float zsT[64][36];   // [d][row], 9.2 KB
    __shared__ __align__(16) float w1s[16][256];  // one 16-d chunk of W1, 16 KB
    __shared__ float w2s[256][11];                // stride 11 -> 2-way max (free)
    __shared__ float as[256], cs[256];
    const int tid = threadIdx.x;
    const int rowbase = blockIdx.x * 32;
    {   // stage z (32x64) transposed: thread -> row tid>>3, d-range (tid&7)*8
        const float* zp = z + (size_t)(rowbase + (tid >> 3)) * 64 + (tid & 7) * 8;
        float4 v0 = *(const float4*)zp;
        float4 v1 = *(const float4*)(zp + 4);
        const int r = tid >> 3, dbase = (tid & 7) * 8;
        zsT[dbase + 0][r] = v0.x; zsT[dbase + 1][r] = v0.y;
        zsT[dbase + 2][r] = v0.z; zsT[dbase + 3][r] = v0.w;
        zsT[dbase + 4][r] = v1.x; zsT[dbase + 5][r] = v1.y;
        zsT[dbase + 6][r] = v1.z; zsT[dbase + 7][r] = v1.w;
    }
    for (int k = tid; k < HD * AT; k += 256) w2s[k / 10][k % 10] = W2[k];
    as[tid] = avec[tid]; cs[tid] = cvec[tid];

    const int rg = tid >> 4, cg = tid & 15;
    const int r0 = rg << 1;                       // 2 rows per thread
    float acc[2][4][4] = {};                      // [row][cblock][u]
    for (int ch = 0; ch < 4; ++ch) {
        __syncthreads();                          // w1s reuse (and staging on ch=0)
        #pragma unroll
        for (int k = 0; k < 16; ++k) {
            int idx = tid + (k << 8);
            ((float*)w1s)[idx] = W1[(ch << 12) + idx];
        }
        __syncthreads();
        #pragma unroll
        for (int dl = 0; dl < 16; ++dl) {
            float zr0 = zsT[(ch << 4) + dl][r0];
            float zr1 = zsT[(ch << 4) + dl][r0 + 1];
            #pragma unroll
            for (int cb = 0; cb < 4; ++cb) {
                float4 wv = *(const float4*)&w1s[dl][(cb << 6) + (cg << 2)];
                float wr[4] = {wv.x, wv.y, wv.z, wv.w};
                #pragma unroll
                for (int u = 0; u < 4; ++u) {
                    acc[0][cb][u] += zr0 * wr[u];
                    acc[1][cb][u] += zr1 * wr[u];
                }
            }
        }
    }
    // epilogue: affine + exact gelu + GEMM2 partials
    float p[2][10] = {};
    #pragma unroll
    for (int cb = 0; cb < 4; ++cb)
        #pragma unroll
        for (int u = 0; u < 4; ++u) {
            const int c = (cb << 6) + (cg << 2) + u;
            const float a = as[c], cc = cs[c];
            #pragma unroll
            for (int ri = 0; ri < 2; ++ri) {
                float h = acc[ri][cb][u] * a + cc;
                h = 0.5f * h * (1.0f + erff(h * 0.70710678118654752f));
                #pragma unroll
                for (int o = 0; o < 10; ++o) p[ri][o] += h * w2s[c][o];
            }
        }
    #pragma unroll
    for (int m = 1; m <= 8; m <<= 1)
        #pragma unroll
        for (int ri = 0; ri < 2; ++ri)
            #pragma unroll
            for (int o = 0; o < 10; ++o) p[ri][o] += __shfl_xor(p[ri][o], m);
    if (cg == 0) {
        #pragma unroll
        for (int ri = 0; ri < 2; ++ri)
            for (int o = 0; o < 10; ++o)
                out_atom[(size_t)(rowbase + r0 + ri) * AT + o] = p[ri][o] + b2[o];
    }
}

// ---------------------------------------------------------------------------
// K4: edges. Block = 2 molecules, 512 threads (8 waves), grid 512.
// LDS 40KB (zs stride 66, uT stride 18 -> only free 2-way conflicts).
// d processed in 4 quarters of 16:
//  Phase A: uT[mol][t][j][dloc] = sum_c Wsym[t][c][d]*z_j[c]  (Wsym symmetric
//    => equals sum_c Wsym[t][d][c]*z_j[c]). Lane = (mol, j); wave wv owns
//    d = qd*16 + wv*2 + {0,1}; c serial in 4 blocks of 16 held in registers.
//    Wsym addresses are wave-uniform -> scalar s_loads (no VMEM, no VGPR cost).
//    No cross-lane reduction needed.
//  Phase B: accE[t][i] += z_i[dq] . uT[mol][t][j][dq]; thread = (mol, j, 4 i's);
//    z reads are 2-address broadcasts, uT reads 2-way at worst.
//  Register peak ~75 floats -> no spill risk. Then per-thread softmax over 5
//  types, direct write in combinations order (edge_index input not needed).
// ---------------------------------------------------------------------------
__global__ __launch_bounds__(512) void k4_edges(const float* __restrict__ z,
                                                const float* __restrict__ Wsym,
                                                float* __restrict__ out_edge) {
    __shared__ float zs[2][32][66];      // 16.9 KB
    __shared__ float uT[2][5][32][18];   // 23.0 KB
    const int tid = threadIdx.x;
    const int mol0 = blockIdx.x * 2;
    // stage z (2 x 32 x 64) as float2, coalesced
    {
        const float2* zg2 = (const float2*)(z + (size_t)mol0 * 2048);
        #pragma unroll
        for (int k = 0; k < 4; ++k) {
            int e = tid + (k << 9);            // 0..2047
            int ml = e >> 10, r = (e >> 5) & 31, c2 = e & 31;
            float2 v = zg2[e];
            zs[ml][r][c2 * 2] = v.x;
            zs[ml][r][c2 * 2 + 1] = v.y;
        }
    }
    // phase-A ids
    const int wv = __builtin_amdgcn_readfirstlane(tid >> 6);  // 0..7 (uniform)
    const int lane = tid & 63;
    const int molA = lane >> 5, jA = lane & 31;
    // phase-B ids
    const int mlB = tid >> 8;                 // 0..1
    const int jg = tid & 31;
    const int i0 = ((tid >> 5) & 7) << 2;     // 0..28
    float accE[5][4] = {};
    __syncthreads();

    for (int qd = 0; qd < 4; ++qd) {
        // ---- Phase A ----
        float accA[5][2] = {};
        const int dpos = (qd << 4) + (wv << 1);
        for (int cb = 0; cb < 4; ++cb) {
            float zr[16];
            #pragma unroll
            for (int m = 0; m < 8; ++m) {
                float2 v = *(const float2*)&zs[molA][jA][(cb << 4) + (m << 1)];
                zr[m * 2] = v.x; zr[m * 2 + 1] = v.y;
            }
            #pragma unroll
            for (int t = 0; t < 5; ++t) {
                const float* wbase = Wsym + (size_t)(t << 12) + (size_t)(cb << 10) + dpos;
                #pragma unroll
                for (int cc = 0; cc < 16; ++cc) {
                    float w0 = wbase[cc * 64];      // wave-uniform -> s_load
                    float w1 = wbase[cc * 64 + 1];
                    accA[t][0] += w0 * zr[cc];
                    accA[t][1] += w1 * zr[cc];
                }
            }
        }
        __syncthreads();                      // phase B of qd-1 done reading uT
        #pragma unroll
        for (int t = 0; t < 5; ++t) {
            float2 w; w.x = accA[t][0]; w.y = accA[t][1];
            *(float2*)&uT[molA][t][jA][wv << 1] = w;
        }
        __syncthreads();                      // uT ready
        // ---- Phase B ----
        #pragma unroll
        for (int cq = 0; cq < 4; ++cq) {
            const int gd = (qd << 4) + (cq << 2);
            float zc[4][4];
            #pragma unroll
            for (int ri = 0; ri < 4; ++ri) {
                float2 a = *(const float2*)&zs[mlB][i0 + ri][gd];
                float2 b = *(const float2*)&zs[mlB][i0 + ri][gd + 2];
                zc[ri][0] = a.x; zc[ri][1] = a.y; zc[ri][2] = b.x; zc[ri][3] = b.y;
            }
            #pragma unroll
            for (int t = 0; t < 5; ++t) {
                float2 ua = *(const float2*)&uT[mlB][t][jg][cq << 2];
                float2 ub = *(const float2*)&uT[mlB][t][jg][(cq << 2) + 2];
                #pragma unroll
                for (int ri = 0; ri < 4; ++ri)
                    accE[t][ri] += zc[ri][0] * ua.x + zc[ri][1] * ua.y
                                 + zc[ri][2] * ub.x + zc[ri][3] * ub.y;
            }
        }
    }
    // softmax over 5 types + write (combinations order, i < j)
    const int ebase = (mol0 + mlB) * EPM;
    #pragma unroll
    for (int ri = 0; ri < 4; ++ri) {
        const int i = i0 + ri, j = jg;
        if (i < j) {
            float l0 = accE[0][ri], l1 = accE[1][ri], l2 = accE[2][ri];
            float l3 = accE[3][ri], l4 = accE[4][ri];
            float m = fmaxf(fmaxf(fmaxf(l0, l1), fmaxf(l2, l3)), l4);
            float e0 = expf(l0 - m), e1 = expf(l1 - m), e2 = expf(l2 - m);
            float e3 = expf(l3 - m), e4 = expf(l4 - m);
            float inv = 1.0f / (e0 + e1 + e2 + e3 + e4);
            int p = 31 * i - ((i * (i - 1)) >> 1) + (j - i - 1);
            float* o = out_edge + (size_t)(ebase + p) * 5;
            o[0] = e0 * inv; o[1] = e1 * inv; o[2] = e2 * inv;
            o[3] = e3 * inv; o[4] = e4 * inv;
        }
    }
}

// ---------------------------------------------------------------------------
extern "C" void kernel_launch(void* const* d_in, const int* in_sizes, int n_in,
                              void* d_out, int out_size, void* d_ws, size_t ws_size,
                              hipStream_t stream) {
    (void)in_sizes; (void)n_in; (void)out_size; (void)ws_size;
    const float* z     = (const float*)d_in[0];
    const float* W1    = (const float*)d_in[1];
    // d_in[2] = b1 : cancels exactly in BN -> unused
    const float* gamma = (const float*)d_in[3];
    const float* beta  = (const float*)d_in[4];
    const float* W2    = (const float*)d_in[5];
    const float* b2    = (const float*)d_in[6];
    const float* bond  = (const float*)d_in[7];
    // d_in[8] = edge_index : deterministic combinations order, recomputed -> unused
    float* out = (float*)d_out;
    float* ws  = (float*)d_ws;

    float* Msum = ws;              // 4096
    float* sumz = ws + 4096;       // 64
    float* avec = ws + 4160;       // 256
    float* cvec = ws + 4416;       // 256
    float* Wsym = ws + 4672;       // 20480

    hipMemsetAsync(ws, 0, (4096 + 64) * sizeof(float), stream);
    k1_moments<<<128, 256, 0, stream>>>(z, Msum, sumz);
    k2w<<<144, 256, 0, stream>>>(Msum, sumz, W1, gamma, beta, bond, avec, cvec, Wsym);
    k3_mlp<<<1024, 256, 0, stream>>>(z, W1, W2, b2, avec, cvec, out);
    k4_edges<<<512, 512, 0, stream>>>(z, Wsym, out + ATOM_OUT);
}